// Round 8
// baseline (3889.960 us; speedup 1.0000x reference)
//
#include <hip/hip_runtime.h>
#include <hip/hip_cooperative_groups.h>
#include <math.h>

namespace cg = cooperative_groups;

// BlockwiseEarlyExitMamba: B=128, L=64, EXIT_POS=32 -> only t<32 matter.
// ONE persistent cooperative kernel (256 blocks x 256 threads, grid.sync()
// between phases), all-phase LDS <= 41.5 KB (static) so the cooperative
// occupancy check passes. Fallback: per-phase normal launches if coop fails.
#define BATCH 128
#define TOKENS 4096

using bf16x8 = __attribute__((ext_vector_type(8))) short;
using f32x4  = __attribute__((ext_vector_type(4))) float;
typedef unsigned short ushort_t;
typedef unsigned int   uint_t;

#define NIP (4*1024*256)
#define NOP (4*256*512)
#define NXP (4*64*512)
#define NFW (256*160)
#define NPREP (NIP+NOP+NXP+NFW)

// ---- LDS layout (bytes); phases alias one static 41984-B region ----
#define LDS_TOTAL 41984
#define GA_STR 40
#define OFF_GAH 0              // P1: 128x32 ushort tiles (10240 B each)
#define OFF_GAL 10240
#define OFF_GWH 20480
#define OFF_GWL 30720          // P1 total 40960
#define OFF3_AH 0              // P3: 64x32 ushort tiles (5120 B each)
#define OFF3_AL 5120
#define OFF3_WH 10240
#define OFF3_WL 15360          // P3 total 20480
#define CAT_STR 168
#define OFF_CH 0               // P0: cat hi/lo (10752 B each)
#define OFF_CL 10752
#define OFF_RED0 21504         // P0 LN reduction (1024 B)
#define SUW 260                // P2: packed-uint u tile stride (uints)
#define OFF_SU 0               // 32*260*4 = 33280 B
#define OFF_SD 33280           // dbc 32x64 f32 = 8192 B -> 41472
#define OFF_RED4 0             // P4 reduction (2048 B)

// ---------------- helpers ----------------
__device__ __forceinline__ float silu_f(float x) { return x / (1.f + __expf(-x)); }
__device__ __forceinline__ ushort_t bf16_rne(float f) {
  unsigned int u = __float_as_uint(f);
  u += 0x7FFFu + ((u >> 16) & 1u);
  return (ushort_t)(u >> 16);
}
__device__ __forceinline__ float bf16_to_f(ushort_t h) {
  return __uint_as_float(((unsigned int)h) << 16);
}
__device__ __forceinline__ void bf16_split(float f, ushort_t& hi, ushort_t& lo) {
  hi = bf16_rne(f);
  lo = bf16_rne(f - bf16_to_f(hi));
}
__device__ __forceinline__ float rec2(ushort_t h, ushort_t l) {
  return bf16_to_f(h) + bf16_to_f(l);
}
__device__ __forceinline__ float rec_packed(uint_t pu) {
  return bf16_to_f((ushort_t)(pu >> 16)) + bf16_to_f((ushort_t)(pu & 0xffff));
}
// unpack 8 packed uints -> hi frag + lo frag
__device__ __forceinline__ void unpack_frag(const uint_t* p, bf16x8& fh, bf16x8& fl) {
  uint4 a = *(const uint4*)p;
  uint4 b = *(const uint4*)(p + 4);
  fh = (bf16x8){(short)(a.x>>16),(short)(a.y>>16),(short)(a.z>>16),(short)(a.w>>16),
                (short)(b.x>>16),(short)(b.y>>16),(short)(b.z>>16),(short)(b.w>>16)};
  fl = (bf16x8){(short)(a.x&0xffff),(short)(a.y&0xffff),(short)(a.z&0xffff),(short)(a.w&0xffff),
                (short)(b.x&0xffff),(short)(b.y&0xffff),(short)(b.z&0xffff),(short)(b.w&0xffff)};
}

struct KParams {
  const float *x, *ep, *ef, *ed, *plw, *plb, *piw, *pib;
  const float *fw, *tng, *tnb, *ipw, *cw, *cb, *xpw, *dpw, *dpb, *alog, *dsk;
  const float *opw, *lng, *lnb, *w1, *b1, *w2, *b2;
  ushort_t *ipw_h, *ipw_l, *opw_h, *opw_l, *xpw_h, *xpw_l, *fw_h, *fw_l;
  ushort_t *feat_h, *feat_l, *xz_h, *xz_l, *y_h, *y_l;
  float *delta;
  float *out;
};

// phase: -1 = all (cooperative, grid.sync between); 0..18 = that phase only.
__global__ __launch_bounds__(256, 1) void coop_kernel(KParams p, int phase) {
  __shared__ __align__(16) char smem[LDS_TOTAL];
  cg::grid_group grid = cg::this_grid();
  const bool all = (phase < 0);
  const int tid = threadIdx.x;
  const int blk = blockIdx.x;
  const int wave = tid >> 6, lane = tid & 63, lm = lane & 15, lq = lane >> 4;

  // ===== phase 0: weight prep (grid-stride) =====
  if (all || phase == 0) {
    for (int i = blk*256 + tid; i < NPREP; i += 256*256) {
      float v; ushort_t h, l;
      if (i < NIP) {
        v = p.ipw[i]; bf16_split(v,h,l); p.ipw_h[i]=h; p.ipw_l[i]=l;
      } else if (i < NIP+NOP) {
        int j = i - NIP;
        v = p.opw[j]; bf16_split(v,h,l); p.opw_h[j]=h; p.opw_l[j]=l;
      } else if (i < NIP+NOP+NXP) {
        int j = i - (NIP+NOP);
        int lay = j >> 15; int r = (j >> 9) & 63, c = j & 511;
        v = (r < 48) ? p.xpw[(size_t)lay*48*512 + r*512 + c] : 0.f;
        bf16_split(v,h,l); p.xpw_h[j]=h; p.xpw_l[j]=l;
      } else {
        int j = i - (NIP+NOP+NXP);
        int r = j / 160, c = j - r*160;
        v = (c < 136) ? p.fw[r*136 + c] : 0.f;
        bf16_split(v,h,l); p.fw_h[j]=h; p.fw_l[j]=l;
      }
    }
  }
  if (all) { __threadfence(); grid.sync(); }

  // ===== phase 1: tokenizer (blocks 0..127) =====
  if ((all || phase == 1) && blk < BATCH) {
    ushort_t* sCh = (ushort_t*)(smem + OFF_CH);
    ushort_t* sCl = (ushort_t*)(smem + OFF_CL);
    float* sRed = (float*)(smem + OFF_RED0);
    const int b = blk;
    for (int idx = tid; idx < 32*160; idx += 256) {
      int t = idx / 160, c = idx - t*160;
      const float* xr = p.x + ((size_t)b*64 + t)*5;
      float x0=xr[0], x1=xr[1], x2=xr[2], x3=xr[3], x4=xr[4];
      float v;
      if (c < 32)       { int pr = min(max((int)x0,0),255); v = p.ep[pr*32+c]; }
      else if (c < 64)    v = x1*p.plw[c-32] + p.plb[c-32];
      else if (c < 96)  { int fl = min(max((int)x2,0),63); v = p.ef[fl*32+(c-64)]; }
      else if (c < 128)   v = x3*p.piw[c-96] + p.pib[c-96];
      else if (c < 136) { int dr = min(max((int)x4,0),1); v = p.ed[dr*8+(c-128)]; }
      else                v = 0.f;
      ushort_t h,l; bf16_split(v,h,l);
      sCh[t*CAT_STR + c] = h; sCl[t*CAT_STR + c] = l;
    }
    __syncthreads();
    f32x4 acc[2][4];
    #pragma unroll
    for (int i=0;i<2;++i)
      #pragma unroll
      for (int j=0;j<4;++j) acc[i][j] = (f32x4){0.f,0.f,0.f,0.f};
    for (int k0 = 0; k0 < 160; k0 += 32) {
      bf16x8 ah[2], al[2];
      #pragma unroll
      for (int mi=0; mi<2; ++mi) {
        int row = mi*16 + lm;
        ah[mi] = *(const bf16x8*)(sCh + row*CAT_STR + k0 + lq*8);
        al[mi] = *(const bf16x8*)(sCl + row*CAT_STR + k0 + lq*8);
      }
      #pragma unroll
      for (int nt=0; nt<4; ++nt) {
        int n = wave*64 + nt*16 + lm;
        bf16x8 wh = *(const bf16x8*)(p.fw_h + (size_t)n*160 + k0 + lq*8);
        bf16x8 wl = *(const bf16x8*)(p.fw_l + (size_t)n*160 + k0 + lq*8);
        #pragma unroll
        for (int mi=0; mi<2; ++mi) {
          acc[mi][nt] = __builtin_amdgcn_mfma_f32_16x16x32_bf16(ah[mi], wh, acc[mi][nt],0,0,0);
          acc[mi][nt] = __builtin_amdgcn_mfma_f32_16x16x32_bf16(ah[mi], wl, acc[mi][nt],0,0,0);
          acc[mi][nt] = __builtin_amdgcn_mfma_f32_16x16x32_bf16(al[mi], wh, acc[mi][nt],0,0,0);
        }
      }
    }
    float s[2][4], q[2][4];
    #pragma unroll
    for (int mi=0; mi<2; ++mi)
      #pragma unroll
      for (int r=0; r<4; ++r) {
        s[mi][r] = acc[mi][0][r]+acc[mi][1][r]+acc[mi][2][r]+acc[mi][3][r];
        q[mi][r] = acc[mi][0][r]*acc[mi][0][r]+acc[mi][1][r]*acc[mi][1][r]
                 + acc[mi][2][r]*acc[mi][2][r]+acc[mi][3][r]*acc[mi][3][r];
      }
    #pragma unroll
    for (int off=1; off<16; off<<=1)
      #pragma unroll
      for (int mi=0; mi<2; ++mi)
        #pragma unroll
        for (int r=0; r<4; ++r) {
          s[mi][r] += __shfl_xor(s[mi][r], off);
          q[mi][r] += __shfl_xor(q[mi][r], off);
        }
    if (lm == 0)
      #pragma unroll
      for (int mi=0; mi<2; ++mi)
        #pragma unroll
        for (int r=0; r<4; ++r) {
          int row = mi*16 + lq*4 + r;
          sRed[row*8 + wave*2]   = s[mi][r];
          sRed[row*8 + wave*2+1] = q[mi][r];
        }
    __syncthreads();
    #pragma unroll
    for (int mi=0; mi<2; ++mi)
      #pragma unroll
      for (int r=0; r<4; ++r) {
        int row = mi*16 + lq*4 + r;
        float S=0.f, Q=0.f;
        #pragma unroll
        for (int w4=0; w4<4; ++w4) { S += sRed[row*8+w4*2]; Q += sRed[row*8+w4*2+1]; }
        float mu = S*(1.f/256.f);
        float rs = rsqrtf(Q*(1.f/256.f) - mu*mu + 1e-5f);
        #pragma unroll
        for (int nt=0; nt<4; ++nt) {
          int n = wave*64 + nt*16 + lm;
          float o = (acc[mi][nt][r]-mu)*rs*p.tng[n] + p.tnb[n];
          ushort_t hh, ll; bf16_split(o, hh, ll);
          size_t gi = ((size_t)(b*32+row))*256 + n;
          p.feat_h[gi] = hh; p.feat_l[gi] = ll;
        }
      }
  }
  if (all) { __threadfence(); grid.sync(); }

  // ===== 4 layers =====
  for (int l = 0; l < 4; ++l) {
    // ---- P1: in_proj GEMM xz[4096,1024] = feat @ ipw^T (128x128 tiles) ----
    if (all || phase == 2 + 4*l) {
      ushort_t* sAh = (ushort_t*)(smem + OFF_GAH);
      ushort_t* sAl = (ushort_t*)(smem + OFF_GAL);
      ushort_t* sWh = (ushort_t*)(smem + OFF_GWH);
      ushort_t* sWl = (ushort_t*)(smem + OFF_GWL);
      const ushort_t* iwh = p.ipw_h + (size_t)l*262144;
      const ushort_t* iwl = p.ipw_l + (size_t)l*262144;
      const int bm = blk >> 3, bn = blk & 7;
      const int wm = (wave>>1)*64, wn = (wave&1)*64;
      f32x4 acc[4][4];
      #pragma unroll
      for (int i=0;i<4;++i)
        #pragma unroll
        for (int j=0;j<4;++j) acc[i][j] = (f32x4){0.f,0.f,0.f,0.f};
      for (int k0 = 0; k0 < 256; k0 += 32) {
        uint4 vah[2], val[2], vwh[2], vwl[2];
        #pragma unroll
        for (int i=0;i<2;++i) {
          int f = tid + i*256;
          int row = f >> 2, kq = (f & 3)*8;
          vah[i] = *(const uint4*)(p.feat_h + ((size_t)(bm*128+row))*256 + k0 + kq);
          val[i] = *(const uint4*)(p.feat_l + ((size_t)(bm*128+row))*256 + k0 + kq);
          vwh[i] = *(const uint4*)(iwh + ((size_t)(bn*128+row))*256 + k0 + kq);
          vwl[i] = *(const uint4*)(iwl + ((size_t)(bn*128+row))*256 + k0 + kq);
        }
        __syncthreads();
        #pragma unroll
        for (int i=0;i<2;++i) {
          int f = tid + i*256;
          int row = f >> 2, kq = (f & 3)*8;
          *(uint4*)(sAh + row*GA_STR + kq) = vah[i];
          *(uint4*)(sAl + row*GA_STR + kq) = val[i];
          *(uint4*)(sWh + row*GA_STR + kq) = vwh[i];
          *(uint4*)(sWl + row*GA_STR + kq) = vwl[i];
        }
        __syncthreads();
        bf16x8 fa[4][2], fb[4][2];
        #pragma unroll
        for (int mi=0; mi<4; ++mi) {
          int r = wm + mi*16 + lm;
          fa[mi][0] = *(const bf16x8*)(sAh + r*GA_STR + lq*8);
          fa[mi][1] = *(const bf16x8*)(sAl + r*GA_STR + lq*8);
        }
        #pragma unroll
        for (int nt=0; nt<4; ++nt) {
          int r = wn + nt*16 + lm;
          fb[nt][0] = *(const bf16x8*)(sWh + r*GA_STR + lq*8);
          fb[nt][1] = *(const bf16x8*)(sWl + r*GA_STR + lq*8);
        }
        #pragma unroll
        for (int mi=0; mi<4; ++mi)
          #pragma unroll
          for (int nt=0; nt<4; ++nt) {
            acc[mi][nt] = __builtin_amdgcn_mfma_f32_16x16x32_bf16(fa[mi][0], fb[nt][0], acc[mi][nt],0,0,0);
            acc[mi][nt] = __builtin_amdgcn_mfma_f32_16x16x32_bf16(fa[mi][0], fb[nt][1], acc[mi][nt],0,0,0);
            acc[mi][nt] = __builtin_amdgcn_mfma_f32_16x16x32_bf16(fa[mi][1], fb[nt][0], acc[mi][nt],0,0,0);
          }
      }
      __syncthreads();
      #pragma unroll
      for (int mi=0; mi<4; ++mi)
        #pragma unroll
        for (int nt=0; nt<4; ++nt) {
          int n = bn*128 + wn + nt*16 + lm;
          #pragma unroll
          for (int r=0; r<4; ++r) {
            int tok = bm*128 + wm + mi*16 + lq*4 + r;
            ushort_t hh, ll; bf16_split(acc[mi][nt][r], hh, ll);
            p.xz_h[(size_t)tok*1024 + n] = hh;
            p.xz_l[(size_t)tok*1024 + n] = ll;
          }
        }
    }
    if (all) { __threadfence(); grid.sync(); }

    // ---- P2: conv+silu + xproj + dtproj + scan + gate (blocks 0..127) ----
    if ((all || phase == 3 + 4*l) && blk < BATCH) {
      const int b = blk;
      uint_t* sU  = (uint_t*)(smem + OFF_SU);    // 32 x SUW packed uints
      float*  sD0 = (float*)(smem + OFF_SD);     // 32 x 64 dbc
      float ureg[64];
      f32x4 ax[2] = {(f32x4){0.f,0.f,0.f,0.f}, (f32x4){0.f,0.f,0.f,0.f}};
      const ushort_t* xwh = p.xpw_h + (size_t)l*32768;
      const ushort_t* xwl = p.xpw_l + (size_t)l*32768;
      const float* cwL = p.cw + (size_t)l*2048;
      const float* cbL = p.cb + (size_t)l*512;
      for (int kh = 0; kh < 2; ++kh) {
        if (kh) __syncthreads();   // prior half's xproj frag reads complete
        // stage xz u-cols [kh*256, +256) packed (hi<<16|lo)
        for (int idx = tid; idx < 32*32; idx += 256) {
          int t = idx >> 5, c8 = (idx & 31)*8;
          const ushort_t* gh = p.xz_h + ((size_t)(b*32+t))*1024 + kh*256 + c8;
          const ushort_t* gl = p.xz_l + ((size_t)(b*32+t))*1024 + kh*256 + c8;
          uint4 vh = *(const uint4*)gh;
          uint4 vl = *(const uint4*)gl;
          uint4 o1, o2;
          o1.x = (vh.x<<16)|(vl.x&0xffffu); o1.y = (vh.x&0xffff0000u)|(vl.x>>16);
          o1.z = (vh.y<<16)|(vl.y&0xffffu); o1.w = (vh.y&0xffff0000u)|(vl.y>>16);
          o2.x = (vh.z<<16)|(vl.z&0xffffu); o2.y = (vh.z&0xffff0000u)|(vl.z>>16);
          o2.z = (vh.w<<16)|(vl.w&0xffffu); o2.w = (vh.w&0xffff0000u)|(vl.w>>16);
          *(uint4*)(sU + t*SUW + c8)     = o1;
          *(uint4*)(sU + t*SUW + c8 + 4) = o2;
        }
        __syncthreads();
        // conv + silu on this half's columns (thread owns col tid)
        {
          int d = kh*256 + tid;
          float c0=cwL[d*4], c1=cwL[d*4+1], c2=cwL[d*4+2], c3=cwL[d*4+3];
          float bias = cbL[d];
          float p3v=0.f, p2v=0.f, p1v=0.f;
          #pragma unroll
          for (int t=0; t<32; ++t) {
            float xv = rec_packed(sU[t*SUW + tid]);
            float a = bias + c0*p3v + c1*p2v + c2*p1v + c3*xv;
            float u = silu_f(a);
            p3v=p2v; p2v=p1v; p1v=xv;
            ureg[kh*32 + t] = u;
            ushort_t hh, ll; bf16_split(u, hh, ll);
            sU[t*SUW + tid] = ((uint_t)hh << 16) | (uint_t)ll;
          }
        }
        __syncthreads();
        // xproj partial over this K-half; wave owns dbc rows [wave*16,+16)
        for (int k0 = 0; k0 < 256; k0 += 32) {
          bf16x8 ah[2], al[2];
          #pragma unroll
          for (int mi=0; mi<2; ++mi)
            unpack_frag(sU + (mi*16+lm)*SUW + k0 + lq*8, ah[mi], al[mi]);
          int wrow = wave*16 + lm;
          bf16x8 wh = *(const bf16x8*)(xwh + (size_t)wrow*512 + kh*256 + k0 + lq*8);
          bf16x8 wl = *(const bf16x8*)(xwl + (size_t)wrow*512 + kh*256 + k0 + lq*8);
          #pragma unroll
          for (int mi=0; mi<2; ++mi) {
            ax[mi] = __builtin_amdgcn_mfma_f32_16x16x32_bf16(ah[mi], wh, ax[mi],0,0,0);
            ax[mi] = __builtin_amdgcn_mfma_f32_16x16x32_bf16(ah[mi], wl, ax[mi],0,0,0);
            ax[mi] = __builtin_amdgcn_mfma_f32_16x16x32_bf16(al[mi], wh, ax[mi],0,0,0);
          }
        }
      }
      #pragma unroll
      for (int mi=0; mi<2; ++mi)
        #pragma unroll
        for (int r=0; r<4; ++r) {
          int row = mi*16 + lq*4 + r;
          sD0[row*64 + wave*16 + lm] = ax[mi][r];
        }
      __syncthreads();
      // dtproj + scan + gate (thread owns cols tid and tid+256)
      const float* dpwL  = p.dpw  + (size_t)l*8192;
      const float* alogL = p.alog + (size_t)l*8192;
      #pragma unroll
      for (int half = 0; half < 2; ++half) {
        int d = half*256 + tid;
        float w[16], cc[16], hh[16];
        #pragma unroll
        for (int r=0; r<16; ++r) w[r] = dpwL[d*16 + r];
        #pragma unroll
        for (int n=0; n<16; ++n) {
          cc[n] = -__expf(alogL[d*16+n]) * 1.4426950408889634f;
          hh[n] = 0.f;
        }
        float bias = p.dpb[l*512 + d], dskv = p.dsk[l*512 + d];
        #pragma unroll
        for (int t=0; t<32; ++t) {
          const float* row = sD0 + t*64;
          float raw = bias;
          #pragma unroll
          for (int r=0; r<16; ++r) raw += w[r]*row[r];
          float dtv = (raw > 20.f) ? raw : __logf(1.f + __expf(raw));
          float uv = ureg[half*32 + t];
          float du = dtv*uv, yv = 0.f;
          #pragma unroll
          for (int n=0; n<16; ++n) {
            float e = exp2f(dtv*cc[n]);
            hh[n] = e*hh[n] + du*row[16+n];
            yv += hh[n]*row[32+n];
          }
          size_t gz = ((size_t)(b*32+t))*1024 + 512 + d;
          float zv = rec2(p.xz_h[gz], p.xz_l[gz]);
          float y = (yv + uv*dskv) * silu_f(zv);
          ushort_t yh, yl; bf16_split(y, yh, yl);
          size_t gy = ((size_t)(b*32+t))*512 + d;
          p.y_h[gy] = yh; p.y_l[gy] = yl;
        }
      }
    }
    if (all) { __threadfence(); grid.sync(); }

    // ---- P3: outproj GEMM delta[4096,256] = y @ opw^T (64x64 tiles) ----
    if (all || phase == 4 + 4*l) {
      ushort_t* sAh = (ushort_t*)(smem + OFF3_AH);
      ushort_t* sAl = (ushort_t*)(smem + OFF3_AL);
      ushort_t* sWh = (ushort_t*)(smem + OFF3_WH);
      ushort_t* sWl = (ushort_t*)(smem + OFF3_WL);
      const ushort_t* owh = p.opw_h + (size_t)l*131072;
      const ushort_t* owl = p.opw_l + (size_t)l*131072;
      const int bm = blk >> 2, bn = blk & 3;
      const int wm = (wave>>1)*32, wn = (wave&1)*32;
      f32x4 acc[2][2];
      #pragma unroll
      for (int i=0;i<2;++i)
        #pragma unroll
        for (int j=0;j<2;++j) acc[i][j] = (f32x4){0.f,0.f,0.f,0.f};
      for (int k0 = 0; k0 < 512; k0 += 32) {
        int row = tid >> 2, kq = (tid & 3)*8;
        uint4 vah = *(const uint4*)(p.y_h + ((size_t)(bm*64+row))*512 + k0 + kq);
        uint4 val = *(const uint4*)(p.y_l + ((size_t)(bm*64+row))*512 + k0 + kq);
        uint4 vwh = *(const uint4*)(owh + ((size_t)(bn*64+row))*512 + k0 + kq);
        uint4 vwl = *(const uint4*)(owl + ((size_t)(bn*64+row))*512 + k0 + kq);
        __syncthreads();
        *(uint4*)(sAh + row*GA_STR + kq) = vah;
        *(uint4*)(sAl + row*GA_STR + kq) = val;
        *(uint4*)(sWh + row*GA_STR + kq) = vwh;
        *(uint4*)(sWl + row*GA_STR + kq) = vwl;
        __syncthreads();
        bf16x8 fa[2][2], fb[2][2];
        #pragma unroll
        for (int mi=0; mi<2; ++mi) {
          int r = wm + mi*16 + lm;
          fa[mi][0] = *(const bf16x8*)(sAh + r*GA_STR + lq*8);
          fa[mi][1] = *(const bf16x8*)(sAl + r*GA_STR + lq*8);
        }
        #pragma unroll
        for (int nt=0; nt<2; ++nt) {
          int r = wn + nt*16 + lm;
          fb[nt][0] = *(const bf16x8*)(sWh + r*GA_STR + lq*8);
          fb[nt][1] = *(const bf16x8*)(sWl + r*GA_STR + lq*8);
        }
        #pragma unroll
        for (int mi=0; mi<2; ++mi)
          #pragma unroll
          for (int nt=0; nt<2; ++nt) {
            acc[mi][nt] = __builtin_amdgcn_mfma_f32_16x16x32_bf16(fa[mi][0], fb[nt][0], acc[mi][nt],0,0,0);
            acc[mi][nt] = __builtin_amdgcn_mfma_f32_16x16x32_bf16(fa[mi][0], fb[nt][1], acc[mi][nt],0,0,0);
            acc[mi][nt] = __builtin_amdgcn_mfma_f32_16x16x32_bf16(fa[mi][1], fb[nt][0], acc[mi][nt],0,0,0);
          }
      }
      __syncthreads();
      #pragma unroll
      for (int mi=0; mi<2; ++mi)
        #pragma unroll
        for (int nt=0; nt<2; ++nt) {
          int n = bn*64 + wn + nt*16 + lm;
          #pragma unroll
          for (int r=0; r<4; ++r) {
            int m = bm*64 + wm + mi*16 + lq*4 + r;
            p.delta[(size_t)m*256 + n] = acc[mi][nt][r];
          }
        }
    }
    if (all) { __threadfence(); grid.sync(); }

    // ---- P4: residual + LN (16 rows per block) ----
    if (all || phase == 5 + 4*l) {
      float* sRed = (float*)(smem + OFF_RED4);
      const int row0 = blk*16;
      float v[16];
      #pragma unroll
      for (int i=0; i<16; ++i) {
        size_t gi = ((size_t)(row0+i))*256 + tid;
        v[i] = p.delta[gi] + rec2(p.feat_h[gi], p.feat_l[gi]);
      }
      #pragma unroll
      for (int i=0; i<16; ++i) {
        float s = v[i], q = v[i]*v[i];
        #pragma unroll
        for (int off=1; off<64; off<<=1) {
          s += __shfl_xor(s, off);
          q += __shfl_xor(q, off);
        }
        if (lane == 0) { sRed[(i*4+wave)*2] = s; sRed[(i*4+wave)*2+1] = q; }
      }
      __syncthreads();
      float gv = p.lng[tid], bv = p.lnb[tid];
      #pragma unroll
      for (int i=0; i<16; ++i) {
        float S=0.f, Q=0.f;
        #pragma unroll
        for (int w4=0; w4<4; ++w4) { S += sRed[(i*4+w4)*2]; Q += sRed[(i*4+w4)*2+1]; }
        float mu = S*(1.f/256.f);
        float rs = rsqrtf(Q*(1.f/256.f) - mu*mu + 1e-5f);
        float o = (v[i]-mu)*rs*gv + bv;
        ushort_t hh, ll; bf16_split(o, hh, ll);
        size_t gi = ((size_t)(row0+i))*256 + tid;
        p.feat_h[gi] = hh; p.feat_l[gi] = ll;
      }
      __syncthreads();
    }
    if (all) { __threadfence(); grid.sync(); }
  }

  // ===== phase 18: classifier (blocks 0..127) =====
  if ((all || phase == 18) && blk < BATCH) {
    float* sH   = (float*)(smem);
    float* sHid = (float*)(smem + 1024);
    const int b = blk;
    size_t gi = ((size_t)(b*32+31))*256 + tid;
    sH[tid] = rec2(p.feat_h[gi], p.feat_l[gi]);
    __syncthreads();
    if (tid < 128) {
      float acc = p.b1[tid];
      const float* wr = p.w1 + (size_t)tid*256;
      #pragma unroll 8
      for (int k=0; k<256; ++k) acc += wr[k]*sH[k];
      sHid[tid] = fmaxf(acc, 0.f);
    }
    __syncthreads();
    if (tid < 2) {
      float o = p.b2[tid];
      const float* w2r = p.w2 + (size_t)tid*128;
      for (int j=0; j<128; ++j) o += w2r[j]*sHid[j];
      p.out[b*2 + tid] = o;
    }
  }
}

// ---------------- launch ----------------
extern "C" void kernel_launch(void* const* d_in, const int* in_sizes, int n_in,
                              void* d_out, int out_size, void* d_ws, size_t ws_size,
                              hipStream_t stream) {
  KParams hp;
  hp.x    = (const float*)d_in[0];
  hp.ep   = (const float*)d_in[1];
  hp.ef   = (const float*)d_in[2];
  hp.ed   = (const float*)d_in[3];
  hp.plw  = (const float*)d_in[4];
  hp.plb  = (const float*)d_in[5];
  hp.piw  = (const float*)d_in[6];
  hp.pib  = (const float*)d_in[7];
  hp.fw   = (const float*)d_in[8];
  hp.tng  = (const float*)d_in[10];
  hp.tnb  = (const float*)d_in[11];
  hp.ipw  = (const float*)d_in[12];
  hp.cw   = (const float*)d_in[13];
  hp.cb   = (const float*)d_in[14];
  hp.xpw  = (const float*)d_in[15];
  hp.dpw  = (const float*)d_in[16];
  hp.dpb  = (const float*)d_in[17];
  hp.alog = (const float*)d_in[18];
  hp.dsk  = (const float*)d_in[19];
  hp.opw  = (const float*)d_in[20];
  hp.lng  = (const float*)d_in[21];
  hp.lnb  = (const float*)d_in[22];
  hp.w1   = (const float*)d_in[23];
  hp.b1   = (const float*)d_in[24];
  hp.w2   = (const float*)d_in[25];
  hp.b2   = (const float*)d_in[26];

  ushort_t* us = (ushort_t*)d_ws;
  hp.ipw_h = us;                      us += (size_t)NIP;
  hp.ipw_l = us;                      us += (size_t)NIP;
  hp.opw_h = us;                      us += (size_t)NOP;
  hp.opw_l = us;                      us += (size_t)NOP;
  hp.xpw_h = us;                      us += (size_t)NXP;
  hp.xpw_l = us;                      us += (size_t)NXP;
  hp.fw_h  = us;                      us += (size_t)NFW;
  hp.fw_l  = us;                      us += (size_t)NFW;
  hp.feat_h = us;                     us += (size_t)TOKENS*256;
  hp.feat_l = us;                     us += (size_t)TOKENS*256;
  hp.xz_h  = us;                      us += (size_t)TOKENS*1024;
  hp.xz_l  = us;                      us += (size_t)TOKENS*1024;
  hp.y_h   = us;                      us += (size_t)TOKENS*512;
  hp.y_l   = us;                      us += (size_t)TOKENS*512;
  hp.delta = (float*)us;
  hp.out   = (float*)d_out;

  int phase_all = -1;
  void* args[] = { &hp, &phase_all };
  hipError_t e = hipLaunchCooperativeKernel((const void*)coop_kernel,
                                            dim3(256), dim3(256), args, 0, stream);
  if (e != hipSuccess) {
    // fallback: per-phase normal launches (kernel boundary = grid barrier)
    for (int ph = 0; ph <= 18; ++ph)
      coop_kernel<<<256, 256, 0, stream>>>(hp, ph);
  }
}

// Round 9
// 494.931 us; speedup vs baseline: 7.8596x; 7.8596x over previous
//
#include <hip/hip_runtime.h>
#include <math.h>

// BlockwiseEarlyExitMamba: B=128, L=64, EXIT_POS=32 -> only t<32 matter.
// 11 kernels: prep + tok + [inproj GEMM + fused-rest]x4 + cls.
// All tensors packed: one uint32 = (bf16_hi << 16) | bf16_lo  (split-bf16).
#define BATCH 128
#define TOKENS 4096

using bf16x8 = __attribute__((ext_vector_type(8))) short;
using f32x4  = __attribute__((ext_vector_type(4))) float;
typedef unsigned short ushort_t;
typedef unsigned int   uint_t;

#define NIP (4*1024*256)
#define NOP (4*256*512)
#define NXP (4*64*512)     // xproj padded 48->64 rows
#define NFW (256*160)      // fusion_w padded 136->160 cols
#define NPREP (NIP+NOP+NXP+NFW)

// ---------------- helpers ----------------
__device__ __forceinline__ float silu_f(float x) { return x / (1.f + __expf(-x)); }
__device__ __forceinline__ ushort_t bf16_rne(float f) {
  unsigned int u = __float_as_uint(f);
  u += 0x7FFFu + ((u >> 16) & 1u);
  return (ushort_t)(u >> 16);
}
__device__ __forceinline__ float bf16_to_f(ushort_t h) {
  return __uint_as_float(((unsigned int)h) << 16);
}
__device__ __forceinline__ uint_t packf(float f) {
  ushort_t h = bf16_rne(f);
  ushort_t l = bf16_rne(f - bf16_to_f(h));
  return ((uint_t)h << 16) | (uint_t)l;
}
__device__ __forceinline__ float unpackf(uint_t u) {
  return bf16_to_f((ushort_t)(u >> 16)) + bf16_to_f((ushort_t)(u & 0xffff));
}
// 8 packed uints (8 k-elements) -> hi bf16x8 + lo bf16x8 via v_perm_b32
union U4V { uint4 q; bf16x8 v; };
__device__ __forceinline__ void unpack_frag8(const uint_t* p, bf16x8& fh, bf16x8& fl) {
  uint4 a = *(const uint4*)p;
  uint4 b = *(const uint4*)(p + 4);
  U4V H, L;
  H.q.x = __builtin_amdgcn_perm(a.y, a.x, 0x07060302u);
  L.q.x = __builtin_amdgcn_perm(a.y, a.x, 0x05040100u);
  H.q.y = __builtin_amdgcn_perm(a.w, a.z, 0x07060302u);
  L.q.y = __builtin_amdgcn_perm(a.w, a.z, 0x05040100u);
  H.q.z = __builtin_amdgcn_perm(b.y, b.x, 0x07060302u);
  L.q.z = __builtin_amdgcn_perm(b.y, b.x, 0x05040100u);
  H.q.w = __builtin_amdgcn_perm(b.w, b.z, 0x07060302u);
  L.q.w = __builtin_amdgcn_perm(b.w, b.z, 0x05040100u);
  fh = H.v; fl = L.v;
}
#define MFMA3(acc, fah, fal, fbh, fbl)                                        \
  acc = __builtin_amdgcn_mfma_f32_16x16x32_bf16(fah, fbh, acc, 0, 0, 0);      \
  acc = __builtin_amdgcn_mfma_f32_16x16x32_bf16(fah, fbl, acc, 0, 0, 0);      \
  acc = __builtin_amdgcn_mfma_f32_16x16x32_bf16(fal, fbh, acc, 0, 0, 0);

// ---------------- prep: fp32 weights -> packed split-bf16 ----------------
__global__ __launch_bounds__(256) void prep_w(
    const float* __restrict__ ipw, const float* __restrict__ opw,
    const float* __restrict__ xpw, const float* __restrict__ fw,
    uint_t* __restrict__ ipw_p, uint_t* __restrict__ opw_p,
    uint_t* __restrict__ xpw_p, uint_t* __restrict__ fw_p) {
  for (int i = blockIdx.x*256 + threadIdx.x; i < NPREP; i += 512*256) {
    if (i < NIP) {
      ipw_p[i] = packf(ipw[i]);
    } else if (i < NIP+NOP) {
      int j = i - NIP;
      opw_p[j] = packf(opw[j]);
    } else if (i < NIP+NOP+NXP) {
      int j = i - (NIP+NOP);
      int lay = j >> 15; int r = (j >> 9) & 63, c = j & 511;
      float v = (r < 48) ? xpw[(size_t)lay*48*512 + r*512 + c] : 0.f;
      xpw_p[j] = packf(v);
    } else {
      int j = i - (NIP+NOP+NXP);
      int r = j / 160, c = j - r*160;
      float v = (c < 136) ? fw[r*136 + c] : 0.f;
      fw_p[j] = packf(v);
    }
  }
}

// ---------------- tokenizer: cat -> GEMM(K=160) -> LN -> feat_p --------------
// 128 blocks (one per batch) x 256 threads (4 waves, wave owns 64 cols)
#define CAT_STR 164
__global__ __launch_bounds__(256) void tok_kernel(
    const float* __restrict__ x,  const float* __restrict__ ep,
    const float* __restrict__ ef, const float* __restrict__ ed,
    const float* __restrict__ plw, const float* __restrict__ plb,
    const float* __restrict__ piw, const float* __restrict__ pib,
    const uint_t* __restrict__ fw_p, const float* __restrict__ g,
    const float* __restrict__ bb, uint_t* __restrict__ feat_p) {
  __shared__ __align__(16) uint_t sC[32*CAT_STR];
  __shared__ float sRed[512];
  const int tid = threadIdx.x, b = blockIdx.x;
  const int wave = tid >> 6, lane = tid & 63, lm = lane & 15, lq = lane >> 4;
  for (int idx = tid; idx < 32*160; idx += 256) {
    int t = idx / 160, c = idx - t*160;
    const float* xr = x + ((size_t)b*64 + t)*5;   // original L=64 stride
    float x0=xr[0], x1=xr[1], x2=xr[2], x3=xr[3], x4=xr[4];
    float v;
    if (c < 32)       { int pr = min(max((int)x0,0),255); v = ep[pr*32+c]; }
    else if (c < 64)    v = x1*plw[c-32] + plb[c-32];
    else if (c < 96)  { int fl = min(max((int)x2,0),63); v = ef[fl*32+(c-64)]; }
    else if (c < 128)   v = x3*piw[c-96] + pib[c-96];
    else if (c < 136) { int dr = min(max((int)x4,0),1); v = ed[dr*8+(c-128)]; }
    else                v = 0.f;
    sC[t*CAT_STR + c] = packf(v);
  }
  __syncthreads();
  f32x4 acc[2][4];
  #pragma unroll
  for (int i=0;i<2;++i)
    #pragma unroll
    for (int j=0;j<4;++j) acc[i][j] = (f32x4){0.f,0.f,0.f,0.f};
  for (int k0 = 0; k0 < 160; k0 += 32) {
    bf16x8 ah[2], al[2];
    #pragma unroll
    for (int mi=0; mi<2; ++mi)
      unpack_frag8(sC + (mi*16+lm)*CAT_STR + k0 + lq*8, ah[mi], al[mi]);
    #pragma unroll
    for (int nt=0; nt<4; ++nt) {
      int n = wave*64 + nt*16 + lm;
      bf16x8 wh, wl;
      unpack_frag8(fw_p + (size_t)n*160 + k0 + lq*8, wh, wl);
      #pragma unroll
      for (int mi=0; mi<2; ++mi) { MFMA3(acc[mi][nt], ah[mi], al[mi], wh, wl); }
    }
  }
  // LN over 256 cols; rows: mi*16+lq*4+r; 4 waves partials
  float s[2][4], q[2][4];
  #pragma unroll
  for (int mi=0; mi<2; ++mi)
    #pragma unroll
    for (int r=0; r<4; ++r) {
      s[mi][r] = acc[mi][0][r]+acc[mi][1][r]+acc[mi][2][r]+acc[mi][3][r];
      q[mi][r] = acc[mi][0][r]*acc[mi][0][r]+acc[mi][1][r]*acc[mi][1][r]
               + acc[mi][2][r]*acc[mi][2][r]+acc[mi][3][r]*acc[mi][3][r];
    }
  #pragma unroll
  for (int off=1; off<16; off<<=1)
    #pragma unroll
    for (int mi=0; mi<2; ++mi)
      #pragma unroll
      for (int r=0; r<4; ++r) {
        s[mi][r] += __shfl_xor(s[mi][r], off);
        q[mi][r] += __shfl_xor(q[mi][r], off);
      }
  if (lm == 0)
    #pragma unroll
    for (int mi=0; mi<2; ++mi)
      #pragma unroll
      for (int r=0; r<4; ++r) {
        int row = mi*16 + lq*4 + r;
        sRed[row*8 + wave*2]   = s[mi][r];
        sRed[row*8 + wave*2+1] = q[mi][r];
      }
  __syncthreads();
  #pragma unroll
  for (int mi=0; mi<2; ++mi)
    #pragma unroll
    for (int r=0; r<4; ++r) {
      int row = mi*16 + lq*4 + r;
      float S=0.f, Q=0.f;
      #pragma unroll
      for (int w4=0; w4<4; ++w4) { S += sRed[row*8+w4*2]; Q += sRed[row*8+w4*2+1]; }
      float mu = S*(1.f/256.f);
      float rs = rsqrtf(Q*(1.f/256.f) - mu*mu + 1e-5f);
      #pragma unroll
      for (int nt=0; nt<4; ++nt) {
        int n = wave*64 + nt*16 + lm;
        float o = (acc[mi][nt][r]-mu)*rs*g[n] + bb[n];
        feat_p[((size_t)(b*32+row))*256 + n] = packf(o);
      }
    }
}

// ---------------- A: in_proj GEMM xz[4096,1024] = feat @ ipw^T ---------------
// grid (8, 32) = (bn, bm), 512 threads = 8 waves (2 M x 4 N), tile 128x128.
#define GA_STR 36
__global__ __launch_bounds__(512) void inproj_kernel(
    const uint_t* __restrict__ feat_p, const uint_t* __restrict__ ipw_p,
    uint_t* __restrict__ xz_p) {
  __shared__ __align__(16) uint_t sA[128*GA_STR];
  __shared__ __align__(16) uint_t sW[128*GA_STR];
  const int tid = threadIdx.x;
  const int wave = tid >> 6, lane = tid & 63, lm = lane & 15, lq = lane >> 4;
  const int wm = (wave & 1)*64, wn = (wave >> 1)*32;
  const int m0 = blockIdx.y*128, n0 = blockIdx.x*128;
  f32x4 acc[4][2];
  #pragma unroll
  for (int i=0;i<4;++i)
    #pragma unroll
    for (int j=0;j<2;++j) acc[i][j] = (f32x4){0.f,0.f,0.f,0.f};
  for (int k0 = 0; k0 < 256; k0 += 32) {
    uint4 va[2], vw[2];
    #pragma unroll
    for (int i=0;i<2;++i) {
      int idx = tid + i*512;           // 0..1023 uint4 slots
      int row = idx >> 3, c4 = (idx & 7)*4;
      va[i] = *(const uint4*)(feat_p + ((size_t)(m0+row))*256 + k0 + c4);
      vw[i] = *(const uint4*)(ipw_p  + ((size_t)(n0+row))*256 + k0 + c4);
    }
    __syncthreads();
    #pragma unroll
    for (int i=0;i<2;++i) {
      int idx = tid + i*512;
      int row = idx >> 3, c4 = (idx & 7)*4;
      *(uint4*)(sA + row*GA_STR + c4) = va[i];
      *(uint4*)(sW + row*GA_STR + c4) = vw[i];
    }
    __syncthreads();
    bf16x8 ah[4], al[4], wh[2], wl[2];
    #pragma unroll
    for (int mi=0; mi<4; ++mi)
      unpack_frag8(sA + (wm+mi*16+lm)*GA_STR + lq*8, ah[mi], al[mi]);
    #pragma unroll
    for (int nt=0; nt<2; ++nt)
      unpack_frag8(sW + (wn+nt*16+lm)*GA_STR + lq*8, wh[nt], wl[nt]);
    #pragma unroll
    for (int mi=0; mi<4; ++mi)
      #pragma unroll
      for (int nt=0; nt<2; ++nt) { MFMA3(acc[mi][nt], ah[mi], al[mi], wh[nt], wl[nt]); }
  }
  #pragma unroll
  for (int mi=0; mi<4; ++mi)
    #pragma unroll
    for (int nt=0; nt<2; ++nt) {
      int n = n0 + wn + nt*16 + lm;
      #pragma unroll
      for (int r=0; r<4; ++r) {
        int tok = m0 + wm + mi*16 + lq*4 + r;
        xz_p[(size_t)tok*1024 + n] = packf(acc[mi][nt][r]);
      }
    }
}

// ---------------- B: conv+silu + xproj + scan + gate + outproj + LN ----------
// 128 blocks (one per batch) x 512 threads (8 waves).
#define SU_STR 516
__global__ __launch_bounds__(512) void layer_kernel(
    const uint_t* __restrict__ xz_p,
    const float* __restrict__ cw, const float* __restrict__ cb,
    const uint_t* __restrict__ xpw_p,
    const float* __restrict__ dpw, const float* __restrict__ dpb,
    const float* __restrict__ alog, const float* __restrict__ dsk,
    const uint_t* __restrict__ opw_p,
    const float* __restrict__ lng, const float* __restrict__ lnb,
    uint_t* __restrict__ feat_p) {
  __shared__ __align__(16) uint_t sU[32*SU_STR];   // u (pre/post conv), then y
  __shared__ float sD[2*32*64];                    // xproj partials
  __shared__ float sRed[512];
  const int tid = threadIdx.x, b = blockIdx.x;
  const int wave = tid >> 6, lane = tid & 63, lm = lane & 15, lq = lane >> 4;
  // stage u-half of xz (32 x 512 packed)
  for (int idx = tid; idx < 4096; idx += 512) {
    int t = idx >> 7, c4 = (idx & 127)*4;
    *(uint4*)(sU + t*SU_STR + c4) =
        *(const uint4*)(xz_p + ((size_t)(b*32+t))*1024 + c4);
  }
  __syncthreads();
  // conv + silu in place; keep u in registers for the scan
  float ureg[32];
  {
    int d = tid;
    const float* cwl = cw + d*4;
    float c0=cwl[0], c1=cwl[1], c2=cwl[2], c3=cwl[3];
    float bias = cb[d];
    float p3=0.f, p2=0.f, p1=0.f;
    #pragma unroll
    for (int t=0; t<32; ++t) {
      float xv = unpackf(sU[t*SU_STR + d]);
      float a = bias + c0*p3 + c1*p2 + c2*p1 + c3*xv;
      float u = silu_f(a);
      p3=p2; p2=p1; p1=xv;
      ureg[t] = u;
      sU[t*SU_STR + d] = packf(u);
    }
  }
  __syncthreads();
  // xproj: 8 waves = 2 K-halves x 4 row-groups(16)
  {
    const int kh = wave >> 2, nr = wave & 3;
    f32x4 ax[2] = {(f32x4){0.f,0.f,0.f,0.f}, (f32x4){0.f,0.f,0.f,0.f}};
    for (int k0 = 0; k0 < 256; k0 += 32) {
      bf16x8 ah[2], al[2];
      #pragma unroll
      for (int mi=0; mi<2; ++mi)
        unpack_frag8(sU + (mi*16+lm)*SU_STR + kh*256 + k0 + lq*8, ah[mi], al[mi]);
      bf16x8 wh, wl;
      unpack_frag8(xpw_p + (size_t)(nr*16+lm)*512 + kh*256 + k0 + lq*8, wh, wl);
      #pragma unroll
      for (int mi=0; mi<2; ++mi) { MFMA3(ax[mi], ah[mi], al[mi], wh, wl); }
    }
    float* dst = sD + kh*2048;
    #pragma unroll
    for (int mi=0; mi<2; ++mi)
      #pragma unroll
      for (int r=0; r<4; ++r) {
        int row = mi*16 + lq*4 + r;
        dst[row*64 + nr*16 + lm] = ax[mi][r];
      }
  }
  __syncthreads();
  for (int i = tid; i < 2048; i += 512) sD[i] += sD[i + 2048];
  __syncthreads();
  // dtproj + scan + gate; thread owns channel d = tid; y -> sU (packed)
  {
    int d = tid;
    float w[16], cc[16], hh[16];
    #pragma unroll
    for (int r=0; r<16; ++r) w[r] = dpw[d*16 + r];
    #pragma unroll
    for (int n=0; n<16; ++n) {
      cc[n] = -__expf(alog[d*16+n]) * 1.4426950408889634f;
      hh[n] = 0.f;
    }
    float bias = dpb[d], dskv = dsk[d];
    #pragma unroll
    for (int t=0; t<32; ++t) {
      const float* row = sD + t*64;
      float raw = bias;
      #pragma unroll
      for (int r=0; r<16; ++r) raw += w[r]*row[r];
      float dtv = (raw > 20.f) ? raw : __logf(1.f + __expf(raw));
      float uv = ureg[t];
      float du = dtv*uv, yv = 0.f;
      #pragma unroll
      for (int n=0; n<16; ++n) {
        float e = exp2f(dtv*cc[n]);
        hh[n] = e*hh[n] + du*row[16+n];
        yv += hh[n]*row[32+n];
      }
      float zv = unpackf(xz_p[((size_t)(b*32+t))*1024 + 512 + d]);
      float y = (yv + uv*dskv) * silu_f(zv);
      sU[t*SU_STR + d] = packf(y);   // own column; xproj reads done (barrier)
    }
  }
  __syncthreads();
  // outproj: wave owns 32 cols; K=512; + residual + LN -> feat_p
  f32x4 ao[2][2];
  #pragma unroll
  for (int i=0;i<2;++i)
    #pragma unroll
    for (int j=0;j<2;++j) ao[i][j] = (f32x4){0.f,0.f,0.f,0.f};
  for (int k0 = 0; k0 < 512; k0 += 32) {
    bf16x8 ah[2], al[2];
    #pragma unroll
    for (int mi=0; mi<2; ++mi)
      unpack_frag8(sU + (mi*16+lm)*SU_STR + k0 + lq*8, ah[mi], al[mi]);
    #pragma unroll
    for (int nt=0; nt<2; ++nt) {
      int n = wave*32 + nt*16 + lm;
      bf16x8 wh, wl;
      unpack_frag8(opw_p + (size_t)n*512 + k0 + lq*8, wh, wl);
      #pragma unroll
      for (int mi=0; mi<2; ++mi) { MFMA3(ao[mi][nt], ah[mi], al[mi], wh, wl); }
    }
  }
  // residual + LN
  float v[2][2][4];
  #pragma unroll
  for (int mi=0; mi<2; ++mi)
    #pragma unroll
    for (int nt=0; nt<2; ++nt)
      #pragma unroll
      for (int r=0; r<4; ++r) {
        int row = mi*16 + lq*4 + r, n = wave*32 + nt*16 + lm;
        v[mi][nt][r] = ao[mi][nt][r]
                     + unpackf(feat_p[((size_t)(b*32+row))*256 + n]);
      }
  float s[2][4], q[2][4];
  #pragma unroll
  for (int mi=0; mi<2; ++mi)
    #pragma unroll
    for (int r=0; r<4; ++r) {
      float a = v[mi][0][r], c = v[mi][1][r];
      s[mi][r] = a + c; q[mi][r] = a*a + c*c;
    }
  #pragma unroll
  for (int off=1; off<16; off<<=1)
    #pragma unroll
    for (int mi=0; mi<2; ++mi)
      #pragma unroll
      for (int r=0; r<4; ++r) {
        s[mi][r] += __shfl_xor(s[mi][r], off);
        q[mi][r] += __shfl_xor(q[mi][r], off);
      }
  if (lm == 0)
    #pragma unroll
    for (int mi=0; mi<2; ++mi)
      #pragma unroll
      for (int r=0; r<4; ++r) {
        int row = mi*16 + lq*4 + r;
        sRed[(row*8 + wave)*2]   = s[mi][r];
        sRed[(row*8 + wave)*2+1] = q[mi][r];
      }
  __syncthreads();
  #pragma unroll
  for (int mi=0; mi<2; ++mi)
    #pragma unroll
    for (int r=0; r<4; ++r) {
      int row = mi*16 + lq*4 + r;
      float S=0.f, Q=0.f;
      #pragma unroll
      for (int w8=0; w8<8; ++w8) { S += sRed[(row*8+w8)*2]; Q += sRed[(row*8+w8)*2+1]; }
      float mu = S*(1.f/256.f);
      float rs = rsqrtf(Q*(1.f/256.f) - mu*mu + 1e-5f);
      #pragma unroll
      for (int nt=0; nt<2; ++nt) {
        int n = wave*32 + nt*16 + lm;
        float o = (v[mi][nt][r]-mu)*rs*lng[n] + lnb[n];
        feat_p[((size_t)(b*32+row))*256 + n] = packf(o);
      }
    }
}

// ---------------- classifier ----------------
__global__ __launch_bounds__(128) void cls_kernel(
    const uint_t* __restrict__ feat_p, const float* __restrict__ w1,
    const float* __restrict__ b1,  const float* __restrict__ w2,
    const float* __restrict__ b2,  float* __restrict__ out) {
  __shared__ float hrow[256];
  __shared__ float hid[128];
  int tid = threadIdx.x, b = blockIdx.x;
  const uint_t* fr = feat_p + ((size_t)(b*32+31))*256;   // EXIT_POS-1 = 31
  hrow[tid]     = unpackf(fr[tid]);
  hrow[tid+128] = unpackf(fr[tid+128]);
  __syncthreads();
  float acc = b1[tid];
  const float* wr = w1 + (size_t)tid*256;
  #pragma unroll 8
  for (int k = 0; k < 256; ++k) acc += wr[k]*hrow[k];
  hid[tid] = fmaxf(acc, 0.f);
  __syncthreads();
  if (tid < 2) {
    float o = b2[tid];
    const float* w2r = w2 + (size_t)tid*128;
    for (int k = 0; k < 128; ++k) o += w2r[k]*hid[k];
    out[b*2 + tid] = o;
  }
}

// ---------------- launch ----------------
extern "C" void kernel_launch(void* const* d_in, const int* in_sizes, int n_in,
                              void* d_out, int out_size, void* d_ws, size_t ws_size,
                              hipStream_t stream) {
  const float* x    = (const float*)d_in[0];
  const float* ep   = (const float*)d_in[1];
  const float* ef   = (const float*)d_in[2];
  const float* ed   = (const float*)d_in[3];
  const float* plw  = (const float*)d_in[4];
  const float* plb  = (const float*)d_in[5];
  const float* piw  = (const float*)d_in[6];
  const float* pib  = (const float*)d_in[7];
  const float* fw   = (const float*)d_in[8];
  const float* tng  = (const float*)d_in[10];
  const float* tnb  = (const float*)d_in[11];
  const float* ipw  = (const float*)d_in[12];
  const float* cw   = (const float*)d_in[13];
  const float* cb   = (const float*)d_in[14];
  const float* xpw  = (const float*)d_in[15];
  const float* dpw  = (const float*)d_in[16];
  const float* dpb  = (const float*)d_in[17];
  const float* alog = (const float*)d_in[18];
  const float* dsk  = (const float*)d_in[19];
  const float* opw  = (const float*)d_in[20];
  const float* lng  = (const float*)d_in[21];
  const float* lnb  = (const float*)d_in[22];
  const float* w1   = (const float*)d_in[23];
  const float* b1   = (const float*)d_in[24];
  const float* w2   = (const float*)d_in[25];
  const float* b2   = (const float*)d_in[26];

  uint_t* up = (uint_t*)d_ws;
  uint_t* ipw_p = up;                 up += (size_t)NIP;
  uint_t* opw_p = up;                 up += (size_t)NOP;
  uint_t* xpw_p = up;                 up += (size_t)NXP;
  uint_t* fw_p  = up;                 up += (size_t)NFW;
  uint_t* feat_p = up;                up += (size_t)TOKENS*256;
  uint_t* xz_p   = up;                up += (size_t)TOKENS*1024;

  prep_w<<<512, 256, 0, stream>>>(ipw, opw, xpw, fw, ipw_p, opw_p, xpw_p, fw_p);
  tok_kernel<<<BATCH, 256, 0, stream>>>(x, ep, ef, ed, plw, plb, piw, pib,
                                        fw_p, tng, tnb, feat_p);
  for (int l = 0; l < 4; ++l) {
    inproj_kernel<<<dim3(8, 32), 512, 0, stream>>>(
        feat_p, ipw_p + (size_t)l*262144, xz_p);
    layer_kernel<<<BATCH, 512, 0, stream>>>(
        xz_p, cw + (size_t)l*2048, cb + (size_t)l*512,
        xpw_p + (size_t)l*32768,
        dpw + (size_t)l*8192, dpb + (size_t)l*512,
        alog + (size_t)l*8192, dsk + (size_t)l*512,
        opw_p + (size_t)l*131072, lng, lnb, feat_p);
  }
  cls_kernel<<<BATCH, 128, 0, stream>>>(feat_p, w1, b1, w2, b2, (float*)d_out);
}